// Round 9
// baseline (180.479 us; speedup 1.0000x reference)
//
#include <hip/hip_runtime.h>
#include <hip/hip_bf16.h>

// BertSelfAttention on MI355X (gfx950). B=2, S=2048, H=1024, heads=16, dh=64.
// Inputs/output float32 (established round 2). Internal compute bf16 MFMA.
//
// Round 9: attention is LDS-throughput-bound (per-wave frag reads ~480
// cyc/iter x 16 waves/CU ~= the measured 54.5us; MFMA/VALU pipes need ~half
// that). Every wave reads the whole Ks/Vs tile, so LDS traffic scales with
// waves-per-q. v2: 4 waves x 32 q-cols (two 16-col MFMA groups per wave),
// halving K/V frag traffic per q. LDS 64KB (Ks16+Vs16+Pb32; mask LDS dropped
// -> C-init from global/L2). 2 blocks/CU. GEMM/converts: r8 unchanged.

typedef __bf16 bf16x8 __attribute__((ext_vector_type(8)));
typedef __bf16 bf16x4 __attribute__((ext_vector_type(4)));
typedef float f32x4 __attribute__((ext_vector_type(4)));

static constexpr int H = 1024;
static constexpr int S = 2048;
static constexpr int NH = 16;
static constexpr int DH = 64;
static constexpr float L2E = 1.4426950408889634f;

#if __has_builtin(__builtin_amdgcn_exp2f)
#define EXP2F(x) __builtin_amdgcn_exp2f(x)
#else
#define EXP2F(x) __builtin_exp2f(x)
#endif

__device__ inline void gll16(const void* g, void* l) {
  __builtin_amdgcn_global_load_lds(
      (const __attribute__((address_space(1))) void*)g,
      (__attribute__((address_space(3))) void*)l, 16, 0, 0);
}

// Fused converts: blocks [0,2048) convert X f32->bf16; blocks [2048,2816)
// transpose-convert Wq/Wk/Wv -> Wt bf16 [n][k] via padded-LDS 64x64 tiles.
__global__ __launch_bounds__(256) void convert_kernel(
    const float* __restrict__ X, const float* __restrict__ W0,
    const float* __restrict__ W1, const float* __restrict__ W2,
    __bf16* __restrict__ Xb, __bf16* __restrict__ Wt) {
  __shared__ float T[64][65];
  const int bid = blockIdx.x, tid = threadIdx.x;
  if (bid < 2048) {
    size_t i = ((size_t)bid * 256 + tid) * 8;
    float4 f0 = *(const float4*)(X + i);
    float4 f1 = *(const float4*)(X + i + 4);
    bf16x8 o;
    o[0] = (__bf16)f0.x; o[1] = (__bf16)f0.y; o[2] = (__bf16)f0.z; o[3] = (__bf16)f0.w;
    o[4] = (__bf16)f1.x; o[5] = (__bf16)f1.y; o[6] = (__bf16)f1.z; o[7] = (__bf16)f1.w;
    *(bf16x8*)(Xb + i) = o;
    return;
  }
  const int wid = bid - 2048;
  const int z = wid >> 8, t = wid & 255;
  const int k0 = (t >> 4) * 64, n0 = (t & 15) * 64;
  const float* W = z == 0 ? W0 : (z == 1 ? W1 : W2);
  __bf16* Wo = Wt + (size_t)z * H * H;
#pragma unroll
  for (int it = 0; it < 4; ++it) {
    int r = it * 16 + (tid >> 4), c = (tid & 15) * 4;
    *(float4*)&T[r][c] = *(const float4*)&W[(size_t)(k0 + r) * H + n0 + c];
  }
  __syncthreads();
#pragma unroll
  for (int it = 0; it < 4; ++it) {
    int n = it * 16 + (tid >> 4), c0 = (tid & 15) * 4;
    bf16x4 o;
#pragma unroll
    for (int j = 0; j < 4; ++j) o[j] = (__bf16)T[c0 + j][n];
    *(bf16x4*)&Wo[(size_t)(n0 + n) * H + k0 + c0] = o;
  }
}

// Fused QKV GEMM (r8): grid (24, 32). blockIdx.x: [0..7]=Q, [8..15]=K,
// [16..23]=V. 128x128 tile, BK=64, bias as MFMA C-init. Q out [bh][s][d]
// (scaled 0.125*L2E), K out [bh][s][d] via LDS-bounce + dwordx4 stores.
// V out [bh][d][s] via bf16x4 strided stores.
__global__ __launch_bounds__(256, 3) void qkv_gemm_kernel(
    const __bf16* __restrict__ Xb, const __bf16* __restrict__ Wt,
    const float* __restrict__ bq, const float* __restrict__ bk,
    const float* __restrict__ bv,
    __bf16* __restrict__ Q, __bf16* __restrict__ K, __bf16* __restrict__ Vt)
{
  __shared__ __bf16 smem[2 * 128 * 64];   // As | Bs (32KB); reused as 4x64x64
  __bf16* As = smem;
  __bf16* Bs = smem + 128 * 64;

  const int tid = threadIdx.x, lane = tid & 63, w = tid >> 6;
  const int quad = lane >> 4, l16 = lane & 15;
  const int wsel = blockIdx.x >> 3;
  const int n0 = (blockIdx.x & 7) * 128;
  const int m0 = blockIdx.y * 128;
  const int wr = w & 1, wc = w >> 1;

  const __bf16* Wsel = Wt + (size_t)wsel * H * H;
  const float* bias = wsel == 0 ? bq : (wsel == 1 ? bk : bv);

  const __bf16* aptr[4];
  const __bf16* bptr[4];
#pragma unroll
  for (int i = 0; i < 4; ++i) {
    int s = w * 256 + i * 64 + lane;
    int row = s >> 3, col = s & 7, sc = col ^ (row & 7);
    aptr[i] = Xb + (size_t)(m0 + row) * H + sc * 8;
    bptr[i] = Wsel + (size_t)(n0 + row) * H + sc * 8;
  }

  f32x4 acc[4][4];
#pragma unroll
  for (int u = 0; u < 4; ++u) {
    float bv_ = bias[n0 + wc * 64 + u * 16 + l16];
#pragma unroll
    for (int t = 0; t < 4; ++t) acc[t][u] = {bv_, bv_, bv_, bv_};
  }

  for (int k0 = 0; k0 < H; k0 += 64) {
    __syncthreads();
#pragma unroll
    for (int i = 0; i < 4; ++i) {
      gll16(aptr[i] + k0, &As[(w * 256 + i * 64) * 8]);
      gll16(bptr[i] + k0, &Bs[(w * 256 + i * 64) * 8]);
    }
    __syncthreads();
#pragma unroll
    for (int kc = 0; kc < 2; ++kc) {
      bf16x8 af[4], bfr[4];
#pragma unroll
      for (int t = 0; t < 4; ++t) {
        int ra = wr * 64 + t * 16 + l16;
        af[t] = *(const bf16x8*)&As[ra * 64 + (((kc * 4 + quad) ^ (ra & 7)) * 8)];
        int rb = wc * 64 + t * 16 + l16;
        bfr[t] = *(const bf16x8*)&Bs[rb * 64 + (((kc * 4 + quad) ^ (rb & 7)) * 8)];
      }
#pragma unroll
      for (int t = 0; t < 4; ++t)
#pragma unroll
        for (int u = 0; u < 4; ++u)
          acc[t][u] = __builtin_amdgcn_mfma_f32_16x16x32_bf16(af[t], bfr[u], acc[t][u], 0, 0, 0);
    }
  }

  const int b = m0 >> 11;
  if (wsel <= 1) {
    __syncthreads();                         // staging LDS now dead
    __bf16* Tr = smem + w * (64 * 64);
    const float scl = wsel == 0 ? 0.125f * L2E : 1.0f;
#pragma unroll
    for (int t = 0; t < 4; ++t)
#pragma unroll
      for (int u = 0; u < 4; ++u)
#pragma unroll
        for (int r = 0; r < 4; ++r) {
          int row = t * 16 + quad * 4 + r;
          int col = u * 16 + l16;
          Tr[row * 64 + (((col >> 3) ^ (row & 7)) * 8 + (col & 7))] =
              (__bf16)(acc[t][u][r] * scl);
        }
    const int head = (n0 + wc * 64) >> 6;
    const int bh = b * NH + head;
    const int si = (m0 & (S - 1)) + wr * 64 + lane;
    __bf16* dst = (wsel == 0 ? Q : K) + ((size_t)bh * S + si) * DH;
#pragma unroll
    for (int c = 0; c < 8; ++c)
      *(bf16x8*)&dst[c * 8] =
          *(const bf16x8*)&Tr[lane * 64 + ((c ^ (lane & 7)) * 8)];
  } else {
#pragma unroll
    for (int u = 0; u < 4; ++u) {
      int n = n0 + wc * 64 + u * 16 + l16;
      int head = n >> 6, d = n & 63;
#pragma unroll
      for (int t = 0; t < 4; ++t) {
        int srow = m0 + wr * 64 + t * 16 + quad * 4;
        int si = srow & (S - 1);
        int bh = b * NH + head;
        bf16x4 o;
#pragma unroll
        for (int r = 0; r < 4; ++r) o[r] = (__bf16)acc[t][u][r];
        *(bf16x4*)&Vt[((size_t)bh * DH + d) * S + si] = o;
      }
    }
  }
}

// Flash attention v2: transposed scores, fixed-max softmax, 4 waves x 32 q.
// grid (16, 32), 256 threads. kv tiles of 128 (measured optimal).
__global__ __launch_bounds__(256, 2) void attn_kernel(
    const __bf16* __restrict__ Q, const __bf16* __restrict__ K,
    const __bf16* __restrict__ Vt, const float* __restrict__ mask,
    float* __restrict__ out)
{
  __shared__ __bf16 Ks[128 * 64];     // [kv][d], 8 ch/row, swizzled, 16KB
  __shared__ __bf16 Vs[64 * 128];     // [d][kv], 16 ch/row, swizzled, 16KB
  __shared__ __bf16 Pb[4 * 32 * 128]; // per-wave P[q32][kv128], swizzled, 32KB

  const int tid = threadIdx.x, lane = tid & 63, w = tid >> 6;  // w: 0..3
  const int quad = lane >> 4, l16 = lane & 15;
  const int bh = blockIdx.y, b = bh >> 4, h = bh & 15;
  const int q0 = blockIdx.x * 128;

  const __bf16* Qb = Q + (size_t)bh * S * DH;    // [s][d]
  const __bf16* Kb = K + (size_t)bh * S * DH;    // [s][d]
  const __bf16* Vb = Vt + (size_t)bh * DH * S;   // [d][s]
  const float* mb = mask + (size_t)b * S;

  // Q B-fragments: wave owns q-cols [q0+w*32, +32) as two 16-col groups
  bf16x8 qf[2][2];
#pragma unroll
  for (int qh = 0; qh < 2; ++qh) {
    int q = q0 + w * 32 + qh * 16 + l16;
#pragma unroll
    for (int kc = 0; kc < 2; ++kc)
      qf[qh][kc] = *(const bf16x8*)&Qb[(size_t)q * DH + kc * 32 + quad * 8];
  }

  // ones A-fragment (row m=0) for the denominator MFMA
  bf16x8 ones_frag;
#pragma unroll
  for (int j = 0; j < 8; ++j) ones_frag[j] = (l16 == 0) ? (__bf16)1.0f : (__bf16)0.0f;

  // staging: thread stages chunks s = i*256 + tid (i=0..3) for K and V
  const __bf16* kp[4];
  const __bf16* vp[4];
#pragma unroll
  for (int i = 0; i < 4; ++i) {
    int s = i * 256 + tid;
    int rk = s >> 3, ck = s & 7;
    kp[i] = Kb + (size_t)rk * DH + ((ck ^ (rk & 7)) * 8);
    int rv = s >> 4, cv = s & 15;
    vp[i] = Vb + (size_t)rv * S + ((cv ^ (rv & 15)) * 8);
  }

  f32x4 o[2][4] = {};
  f32x4 o4[2] = {};   // per-group denominator (row 0 of ones-MFMA)

  for (int kv0 = 0; kv0 < S; kv0 += 128) {
    __syncthreads();
#pragma unroll
    for (int i = 0; i < 4; ++i) {
      gll16(kp[i] + (size_t)kv0 * DH, &Ks[(i * 256 + w * 64) * 8]);
      gll16(vp[i] + kv0, &Vs[(i * 256 + w * 64) * 8]);
    }
    __syncthreads();

    // scores S^T (log2 domain), C-init = mask*log2e from L2; P -> Pb
#pragma unroll
    for (int t = 0; t < 8; ++t) {
      int rk = t * 16 + l16;
      bf16x8 k0f = *(const bf16x8*)&Ks[(rk * 8 + (quad ^ (rk & 7))) * 8];
      bf16x8 k1f = *(const bf16x8*)&Ks[(rk * 8 + ((4 + quad) ^ (rk & 7))) * 8];
      float4 mv = *(const float4*)&mb[kv0 + t * 16 + quad * 4];
      int c3 = 2 * t + (quad >> 1);
#pragma unroll
      for (int qh = 0; qh < 2; ++qh) {
        f32x4 z = {mv.x * L2E, mv.y * L2E, mv.z * L2E, mv.w * L2E};
        z = __builtin_amdgcn_mfma_f32_16x16x32_bf16(k0f, qf[qh][0], z, 0, 0, 0);
        f32x4 sc = __builtin_amdgcn_mfma_f32_16x16x32_bf16(k1f, qf[qh][1], z, 0, 0, 0);
        bf16x4 pk;
#pragma unroll
        for (int r = 0; r < 4; ++r) pk[r] = (__bf16)EXP2F(sc[r]);
        *(bf16x4*)&Pb[(w * 32 + qh * 16 + l16) * 128 +
                      ((c3 ^ l16) & 15) * 8 + (quad & 1) * 4] = pk;
      }
    }

    // O^T += V^T P^T ; ones-row MFMA accumulates denominators
#pragma unroll
    for (int kc = 0; kc < 4; ++kc) {
      bf16x8 pf[2];
#pragma unroll
      for (int qh = 0; qh < 2; ++qh)
        pf[qh] = *(const bf16x8*)&Pb[(w * 32 + qh * 16 + l16) * 128 +
                                     (((4 * kc + quad) ^ l16) & 15) * 8];
#pragma unroll
      for (int u = 0; u < 4; ++u) {
        int d = u * 16 + l16;
        bf16x8 vf = *(const bf16x8*)&Vs[(d * 16 + (((4 * kc + quad) ^ l16) & 15)) * 8];
#pragma unroll
        for (int qh = 0; qh < 2; ++qh)
          o[qh][u] = __builtin_amdgcn_mfma_f32_16x16x32_bf16(vf, pf[qh], o[qh][u], 0, 0, 0);
      }
#pragma unroll
      for (int qh = 0; qh < 2; ++qh)
        o4[qh] = __builtin_amdgcn_mfma_f32_16x16x32_bf16(ones_frag, pf[qh], o4[qh], 0, 0, 0);
    }
  }

  // epilogue: per group, denominator for q-col l16 on lane l16 (quad 0), reg 0
#pragma unroll
  for (int qh = 0; qh < 2; ++qh) {
    float l_q = __shfl(o4[qh][0], l16, 64);
    float invl = 1.0f / l_q;
    int q = q0 + w * 32 + qh * 16 + l16;
#pragma unroll
    for (int u = 0; u < 4; ++u) {
      float4 st = {o[qh][u][0] * invl, o[qh][u][1] * invl,
                   o[qh][u][2] * invl, o[qh][u][3] * invl};
      *(float4*)&out[((size_t)b * S + q) * H + h * DH + u * 16 + quad * 4] = st;
    }
  }
}

extern "C" void kernel_launch(void* const* d_in, const int* in_sizes, int n_in,
                              void* d_out, int out_size, void* d_ws, size_t ws_size,
                              hipStream_t stream) {
  const float* X    = (const float*)d_in[0];
  const float* mask = (const float*)d_in[1];
  const float* Wq   = (const float*)d_in[2];
  const float* bq   = (const float*)d_in[3];
  const float* Wk   = (const float*)d_in[4];
  const float* bk   = (const float*)d_in[5];
  const float* Wv   = (const float*)d_in[6];
  const float* bv   = (const float*)d_in[7];
  float* out = (float*)d_out;

  const size_t per = (size_t)2 * NH * S * DH;   // 4M elems
  __bf16* Qws  = (__bf16*)d_ws;                 // 8MB  [bh][s][d]
  __bf16* Kws  = Qws + per;                     // 8MB  [bh][s][d]
  __bf16* Vtws = Kws + per;                     // 8MB  [bh][d][s]

  // GEMM-phase scratch inside d_out (16MB); attn overwrites all of d_out.
  __bf16* Xb = (__bf16*)d_out;                  // 8MB
  __bf16* Wt = Xb + per;                        // 3 x 2MB

  convert_kernel<<<2816, 256, 0, stream>>>(X, Wq, Wk, Wv, Xb, Wt);
  qkv_gemm_kernel<<<dim3(24, 32), 256, 0, stream>>>(Xb, Wt, bq, bk, bv,
                                                    Qws, Kws, Vtws);
  attn_kernel<<<dim3(16, 32), 256, 0, stream>>>(Qws, Kws, Vtws, mask, out);
}